// Round 18
// baseline (187.840 us; speedup 1.0000x reference)
//
#include <hip/hip_runtime.h>
#include <hip/hip_bf16.h>

// GNN forward: pre-Linear -> GATConv(6 heads, self-loops, edge softmax) -> concat -> Linear
// - Aggregation identity: sum_e coef_e*(h[s]@Wg) = (sum_e coef_e*h[s])@Wg -> gather 128B bf16 rows
// - a_src/a_dst computed as k_pre REGISTER EPILOGUE (f32 acc + shfl-reduce)
// - Self-loops handled inline in k_agg (edata/CSR hold only the EE real edges)
// - Per-edge softmax weights computed once in k_fill -> 16B f16 records {src, 6 x f16 w}
// - k_agg: readfirstlane scalar record loads, 8-edge unroll
// - R18: k_pre BARRIER-FREE K-loop — all of Wt (64KB bf16) resident in LDS (XOR-swizzled,
//   staged once), A-fragments register-direct. R15-R17 showed ~58us invariant under reg-pipeline
//   and K-split (24 waves/CU): the per-iteration vmcnt(0)-drain at the staging barrier was the
//   serializer. No barriers in the K-loop -> x-load latency pipelines within each wave.
// - R12/R13 lesson: launch-fusion bundles were net NEGATIVE. 8-kernel chain kept.
// - NOTE(R6/R7): do NOT fuse a_src/a_dst as extra MFMA columns (80-col B tile) -> replay divergence.
// N=50000, E=800000, CUR=512, HID=64, OUT=64, HEADS=6

#define NN    50000
#define EE    800000
#define CURD  512
#define HIDD  64
#define FD    384        // HEADS*OUT
#define CATK  448        // HID + FD

typedef __attribute__((ext_vector_type(8))) short short8;
typedef __attribute__((ext_vector_type(4))) float f32x4;

static __device__ __forceinline__ float b2f(unsigned short u) {
    union { unsigned int i; float f; } x; x.i = ((unsigned int)u) << 16; return x.f;
}
static __device__ __forceinline__ unsigned short f2b(float f) {
    unsigned int x = __float_as_uint(f);
    unsigned int r = (x + 0x7fffu + ((x >> 16) & 1u)) >> 16;
    return (unsigned short)r;
}
static __device__ __forceinline__ unsigned int packbf(float a, float b) {
    return (unsigned int)f2b(a) | ((unsigned int)f2b(b) << 16);
}
static __device__ __forceinline__ unsigned short f2h(float f) {
    _Float16 h = (_Float16)f; unsigned short u; __builtin_memcpy(&u, &h, 2); return u;
}
static __device__ __forceinline__ float h2f(unsigned short u) {
    _Float16 h; __builtin_memcpy(&h, &u, 2); return (float)h;
}
static __device__ __forceinline__ float lrelu(float v, float a) { return v > 0.f ? v : a * v; }

// ---------------- k_setup: init + detect + 3 weight transposes + watt(+bias proj) ----------
#define B_INIT 196
#define B_DET  196
#define B_TRWP 197            // 128 blocks: Wt[c][k]=Wp[k][c]
#define B_TRWL 325            // 112 blocks: Wlt[c][k]=Wl[k][c]
#define B_TRWG 437            // 96 blocks:  Wgt[h][c][k]=Wg[k][h*64+c]
#define B_WATT 533            // 2 blocks:   wsv/wdv[h][k] + bws/bwd[h]
#define B_TOT  535

__global__ void k_setup(const int* __restrict__ ei,
                        const float* __restrict__ Wp, const float* __restrict__ bp,
                        const float* __restrict__ Wl, const float* __restrict__ Wg,
                        const float* __restrict__ atts, const float* __restrict__ attd,
                        unsigned int* __restrict__ counts, unsigned int* __restrict__ cursor,
                        unsigned int* __restrict__ flag,
                        unsigned short* __restrict__ Wt, unsigned short* __restrict__ Wlt,
                        unsigned short* __restrict__ Wgt,
                        float* __restrict__ wsv, float* __restrict__ wdv,
                        float* __restrict__ bws, float* __restrict__ bwd) {
    __shared__ unsigned int anyv;
    const int b = blockIdx.x, t = threadIdx.x;
    if (b < B_INIT) {
        int i = b * 256 + t;
        if (i < NN) { counts[i] = 0u; cursor[i] = 0u; }
    } else if (b == B_DET) {
        if (t == 0) anyv = 0u;
        __syncthreads();
        unsigned int v = 0;
        for (int i = t; i < 2048; i += 256) v |= (unsigned int)ei[2 * i + 1];
        atomicOr(&anyv, v);
        __syncthreads();
        if (t == 0) *flag = (anyv == 0u) ? 1u : 0u;   // 1 => int64 layout
    } else if (b < B_TRWL) {
        int i = (b - B_TRWP) * 256 + t;               // Wt[c][k]=Wp[k][c], K=512
        int c = i >> 9, k = i & 511;
        Wt[i] = f2b(Wp[k * 64 + c]);
    } else if (b < B_TRWG) {
        int i = (b - B_TRWL) * 256 + t;
        if (i < 64 * CATK) {
            int c = i / CATK, k = i - c * CATK;
            Wlt[i] = f2b(Wl[k * 64 + c]);
        }
    } else if (b < B_WATT) {
        int i = (b - B_TRWG) * 256 + t;
        int hd = i >> 12, rem = i & 4095, c = rem >> 6, k = rem & 63;
        Wgt[i] = f2b(Wg[k * FD + hd * 64 + c]);
    } else {
        int j = (b - B_WATT) * 256 + t;               // 384 total; whole waves valid/invalid
        if (j < 384) {
            int hd = j >> 6, k = j & 63;
            float s = 0.f, d = 0.f;
            for (int c = 0; c < 64; c++) {
                float w = Wg[k * FD + hd * 64 + c];
                s = fmaf(w, atts[hd * 64 + c], s);
                d = fmaf(w, attd[hd * 64 + c], d);
            }
            wsv[j] = s; wdv[j] = d;
            float pbs = bp[k] * s, pbd = bp[k] * d;
            #pragma unroll
            for (int o = 32; o > 0; o >>= 1) {
                pbs += __shfl_xor(pbs, o, 64);
                pbd += __shfl_xor(pbd, o, 64);
            }
            if ((t & 63) == 0) { bws[hd] = pbs; bwd[hd] = pbd; }
        }
    }
}

// ---- K1: hb = bf16(x @ W_pre + b_pre); B resident in LDS (swizzled), barrier-free K-loop ----
__global__ __launch_bounds__(256) void k_pre(const float* __restrict__ x,
                                             const unsigned short* __restrict__ Wt,
                                             const float* __restrict__ bp,
                                             const float* __restrict__ wsv,
                                             const float* __restrict__ wdv,
                                             const float* __restrict__ bws,
                                             const float* __restrict__ bwd,
                                             unsigned short* __restrict__ hb,
                                             float* __restrict__ asrcP, float* __restrict__ adstP) {
    __shared__ __align__(16) unsigned short Bs[64][512];   // 64KB, col XOR-swizzled
    const int t  = threadIdx.x;
    const int n0 = blockIdx.x * 64;
    const int w = t >> 6, l = t & 63;
    const int fr = l & 15, fq = l >> 4;
    int arow = n0 + w * 16 + fr; if (arow >= NN) arow = NN - 1;   // this lane's A row

    // stage ALL of Wt once: 4096 8-elem chunks; swizzle col8 -> col8 ^ (row&7)
    #pragma unroll
    for (int j = 0; j < 16; j++) {
        const int ci = t + 256 * j;          // chunk index
        const int r  = ci >> 6;              // row 0..63
        const int c8 = ci & 63;              // 8-elem chunk 0..63
        const uint4 v = *(const uint4*)(Wt + (size_t)r * CURD + c8 * 8);
        *(uint4*)&Bs[r][(c8 ^ (r & 7)) * 8] = v;
    }
    __syncthreads();   // the ONLY barrier

    f32x4 acc[4];
    #pragma unroll
    for (int nb = 0; nb < 4; nb++) acc[nb] = (f32x4){0.f, 0.f, 0.f, 0.f};

    #pragma unroll 2
    for (int kt = 0; kt < CURD; kt += 64) {
        // A: register-direct fragment loads (R11-proven layout), 4 float4 per K-tile
        const float* xr = x + (size_t)arow * CURD + kt;
        const float4 L0 = *(const float4*)(xr + 0 * 32 + fq * 8);
        const float4 L1 = *(const float4*)(xr + 0 * 32 + fq * 8 + 4);
        const float4 L2 = *(const float4*)(xr + 1 * 32 + fq * 8);
        const float4 L3 = *(const float4*)(xr + 1 * 32 + fq * 8 + 4);
        unsigned int af0w[4] = {packbf(L0.x,L0.y), packbf(L0.z,L0.w),
                                packbf(L1.x,L1.y), packbf(L1.z,L1.w)};
        unsigned int af1w[4] = {packbf(L2.x,L2.y), packbf(L2.z,L2.w),
                                packbf(L3.x,L3.y), packbf(L3.z,L3.w)};
        short8 af0, af1;
        __builtin_memcpy(&af0, af0w, 16);
        __builtin_memcpy(&af1, af1w, 16);
        #pragma unroll
        for (int nb = 0; nb < 4; nb++) {
            const int br = nb * 16 + fr;
            const int c0 = kt + 0 * 32 + fq * 8;
            short8 bf = *(const short8*)&Bs[br][((c0 >> 3) ^ (br & 7)) * 8];
            acc[nb] = __builtin_amdgcn_mfma_f32_16x16x32_bf16(af0, bf, acc[nb], 0, 0, 0);
        }
        #pragma unroll
        for (int nb = 0; nb < 4; nb++) {
            const int br = nb * 16 + fr;
            const int c1 = kt + 1 * 32 + fq * 8;
            short8 bf = *(const short8*)&Bs[br][((c1 >> 3) ^ (br & 7)) * 8];
            acc[nb] = __builtin_amdgcn_mfma_f32_16x16x32_bf16(af1, bf, acc[nb], 0, 0, 0);
        }
    }

    // C write: frag col=nb*16+fr, row=w*16+fq*4+r
    #pragma unroll
    for (int nb = 0; nb < 4; nb++) {
        const int col = nb * 16 + fr;
        const float bias = bp[col];
        #pragma unroll
        for (int r = 0; r < 4; r++) {
            const int row = n0 + w * 16 + fq * 4 + r;
            if (row < NN) hb[(size_t)row * HIDD + col] = f2b(acc[nb][r] + bias);
        }
    }
    // attention-logit epilogue: asrc[row][hd] = sum_col acc[row][col]*wsv[hd][col] + bws[hd]
    for (int hd = 0; hd < 6; hd++) {
        float wsl[4], wdl[4];
        #pragma unroll
        for (int nb = 0; nb < 4; nb++) {
            wsl[nb] = wsv[hd * 64 + nb * 16 + fr];
            wdl[nb] = wdv[hd * 64 + nb * 16 + fr];
        }
        float ps[4], pd[4];
        #pragma unroll
        for (int r = 0; r < 4; r++) {
            ps[r] = acc[0][r] * wsl[0];
            pd[r] = acc[0][r] * wdl[0];
            #pragma unroll
            for (int nb = 1; nb < 4; nb++) {
                ps[r] = fmaf(acc[nb][r], wsl[nb], ps[r]);
                pd[r] = fmaf(acc[nb][r], wdl[nb], pd[r]);
            }
        }
        #pragma unroll
        for (int o = 1; o < 16; o <<= 1) {
            #pragma unroll
            for (int r = 0; r < 4; r++) {
                ps[r] += __shfl_xor(ps[r], o, 64);
                pd[r] += __shfl_xor(pd[r], o, 64);
            }
        }
        if (fr == 0) {
            const float bs = bws[hd], bd = bwd[hd];
            #pragma unroll
            for (int r = 0; r < 4; r++) {
                const int row = n0 + w * 16 + fq * 4 + r;
                if (row < NN) {
                    asrcP[(size_t)row * 8 + hd] = ps[r] + bs;
                    adstP[(size_t)row * 8 + hd] = pd[r] + bd;
                }
            }
        }
    }
}

// ---------------- in-degree histogram (real edges only) ----------------
__global__ void k_hist(const int* __restrict__ ei, const unsigned int* __restrict__ flag,
                       unsigned int* __restrict__ counts) {
    int e = blockIdx.x * 256 + threadIdx.x;
    if (e >= EE) return;
    const bool wide = (*flag != 0u);
    int d = wide ? ei[2 * (EE + e)] : ei[EE + e];
    atomicAdd(&counts[d], 1u);
}

// ---------------- scan phase 1: per-block sums ----------------
__global__ __launch_bounds__(256) void k_bsum(const unsigned int* __restrict__ counts,
                                              unsigned int* __restrict__ bsum) {
    __shared__ unsigned int wt[4];
    const int t = threadIdx.x, w = t >> 6, l = t & 63;
    int i = blockIdx.x * 256 + t;
    unsigned int v = (i < NN) ? counts[i] : 0u;
    #pragma unroll
    for (int o = 32; o > 0; o >>= 1) v += __shfl_xor(v, o, 64);
    if (l == 0) wt[w] = v;
    __syncthreads();
    if (t == 0) bsum[blockIdx.x] = wt[0] + wt[1] + wt[2] + wt[3];
}

// ---------------- scan phase 2: offsets (inline redundant scan of 196 block sums) ----------------
__global__ __launch_bounds__(256) void k_off(const unsigned int* __restrict__ counts,
                                             const unsigned int* __restrict__ bsum,
                                             unsigned int* __restrict__ offsets) {
    __shared__ unsigned int sc[256];
    __shared__ unsigned int wt[4];
    const int t = threadIdx.x, w = t >> 6, l = t & 63;
    const int nb = (NN + 255) / 256;   // 196
    unsigned int bv = (t < nb) ? bsum[t] : 0u;
    sc[t] = bv;
    __syncthreads();
    for (int o = 1; o < 256; o <<= 1) {
        unsigned int xv = (t >= o) ? sc[t - o] : 0u;
        __syncthreads();
        sc[t] += xv;
        __syncthreads();
    }
    const unsigned int bpre = sc[blockIdx.x] -
        ((blockIdx.x < nb) ? bsum[blockIdx.x] : 0u);   // exclusive prefix for this block

    int i = blockIdx.x * 256 + t;
    unsigned int v = (i < NN) ? counts[i] : 0u;
    unsigned int incl = v;
    #pragma unroll
    for (int o = 1; o < 64; o <<= 1) {
        unsigned int xv = __shfl_up(incl, o, 64);
        if (l >= o) incl += xv;
    }
    if (l == 63) wt[w] = incl;
    __syncthreads();
    unsigned int woff = 0;
    #pragma unroll
    for (int ww = 0; ww < 4; ww++) woff += (ww < w) ? wt[ww] : 0u;
    const unsigned int base = bpre + woff;
    if (i < NN) offsets[i] = base + incl - v;
    if (i == NN - 1) offsets[NN] = base + incl;
}

// ---------------- CSR fill + per-edge weights: edata[pos] = {src, 6 x f16 w} (16B) ----------------
__global__ void k_fill(const int* __restrict__ ei, const unsigned int* __restrict__ flag,
                       const unsigned int* __restrict__ offsets, unsigned int* __restrict__ cursor,
                       const float* __restrict__ asrcP, const float* __restrict__ adstP,
                       uint4* __restrict__ edata) {
    int e = blockIdx.x * 256 + threadIdx.x;
    if (e >= EE) return;
    const bool wide = (*flag != 0u);
    const int s = wide ? ei[2 * e] : ei[e];
    const int d = wide ? ei[2 * (EE + e)] : ei[EE + e];
    unsigned int pos = offsets[d] + atomicAdd(&cursor[d], 1u);
    const float4 s0 = *(const float4*)(asrcP + (size_t)s * 8);
    const float2 s1 = *(const float2*)(asrcP + (size_t)s * 8 + 4);
    const float4 d0 = *(const float4*)(adstP + (size_t)d * 8);
    const float2 d1 = *(const float2*)(adstP + (size_t)d * 8 + 4);
    const float as[6] = {s0.x, s0.y, s0.z, s0.w, s1.x, s1.y};
    const float ad[6] = {d0.x, d0.y, d0.z, d0.w, d1.x, d1.y};
    unsigned short wh[6];
    #pragma unroll
    for (int hd = 0; hd < 6; hd++) {
        float a = as[hd] + ad[hd];
        a = fmaxf(a, 0.2f * a);                 // leaky_relu 0.2
        wh[hd] = f2h(__expf(a));                // shift skipped: alpha O(1), softmax shift-invariant
    }
    uint4 u;
    u.x = (unsigned int)s;
    u.y = (unsigned int)wh[0] | ((unsigned int)wh[1] << 16);
    u.z = (unsigned int)wh[2] | ((unsigned int)wh[3] << 16);
    u.w = (unsigned int)wh[4] | ((unsigned int)wh[5] << 16);
    edata[pos] = u;
}

// ---- k_agg: self-loop inline + scalar f16-record loads (8-edge unroll) + row gather ----
#define W6H(u, nm) \
    const float nm[6] = {h2f(u.y & 0xffff), h2f(u.y >> 16), h2f(u.z & 0xffff), \
                         h2f(u.z >> 16),    h2f(u.w & 0xffff), h2f(u.w >> 16)};

__global__ __launch_bounds__(256) void k_agg(const unsigned int* __restrict__ offsets,
                                             const uint4* __restrict__ edata,
                                             const float* __restrict__ asrcP,
                                             const float* __restrict__ adstP,
                                             const unsigned short* __restrict__ hb,
                                             unsigned short* __restrict__ gb) {
    const int n = blockIdx.x * 4 + (threadIdx.x >> 6);  // one wave per node
    if (n >= NN) return;
    const int l = threadIdx.x & 63;
    const unsigned int e0 = __builtin_amdgcn_readfirstlane(offsets[n]);
    const unsigned int e1 = __builtin_amdgcn_readfirstlane(offsets[n + 1]);
    float acc[6], den[6];
    {   // self loop: w = exp(lrelu(asrc[n]+adst[n])), contribution w*hb[n]
        const float4 a0 = *(const float4*)(asrcP + (size_t)n * 8);
        const float2 a1 = *(const float2*)(asrcP + (size_t)n * 8 + 4);
        const float4 d0 = *(const float4*)(adstP + (size_t)n * 8);
        const float2 d1 = *(const float2*)(adstP + (size_t)n * 8 + 4);
        const float as[6] = {a0.x, a0.y, a0.z, a0.w, a1.x, a1.y};
        const float ad[6] = {d0.x, d0.y, d0.z, d0.w, d1.x, d1.y};
        const float hvn = b2f(hb[(size_t)n * HIDD + l]);
        #pragma unroll
        for (int hd = 0; hd < 6; hd++) {
            float a = as[hd] + ad[hd];
            a = fmaxf(a, 0.2f * a);
            const float wv = __expf(a);
            acc[hd] = wv * hvn;
            den[hd] = wv;
        }
    }

    unsigned int e = e0;
    for (; e + 8 <= e1; e += 8) {
        const unsigned int eu = __builtin_amdgcn_readfirstlane(e);  // uniform -> s_load records
        uint4 r[8];
        #pragma unroll
        for (int j = 0; j < 8; j++) r[j] = edata[(size_t)eu + j];
        float hv[8];
        #pragma unroll
        for (int j = 0; j < 8; j++) hv[j] = b2f(hb[(size_t)r[j].x * HIDD + l]);
        #pragma unroll
        for (int j = 0; j < 8; j++) {
            W6H(r[j], wj)
            #pragma unroll
            for (int hd = 0; hd < 6; hd++) {
                acc[hd] = fmaf(wj[hd], hv[j], acc[hd]);
                den[hd] += wj[hd];
            }
        }
    }
    for (; e + 4 <= e1; e += 4) {
        const unsigned int eu = __builtin_amdgcn_readfirstlane(e);
        uint4 r[4];
        #pragma unroll
        for (int j = 0; j < 4; j++) r[j] = edata[(size_t)eu + j];
        float hv[4];
        #pragma unroll
        for (int j = 0; j < 4; j++) hv[j] = b2f(hb[(size_t)r[j].x * HIDD + l]);
        #pragma unroll
        for (int j = 0; j < 4; j++) {
            W6H(r[j], wj)
            #pragma unroll
            for (int hd = 0; hd < 6; hd++) {
                acc[hd] = fmaf(wj[hd], hv[j], acc[hd]);
                den[hd] += wj[hd];
            }
        }
    }
    for (; e < e1; e++) {
        const unsigned int eu = __builtin_amdgcn_readfirstlane(e);
        const uint4 u = edata[(size_t)eu];
        const float hv = b2f(hb[(size_t)u.x * HIDD + l]);
        W6H(u, wv)
        #pragma unroll
        for (int hd = 0; hd < 6; hd++) {
            acc[hd] = fmaf(wv[hd], hv, acc[hd]);
            den[hd] += wv[hd];
        }
    }
    #pragma unroll
    for (int hd = 0; hd < 6; hd++)
        gb[(size_t)n * FD + hd * 64 + l] = f2b(acc[hd] / den[hd]);
}

// ---- k_tail: out = [hb | lrelu(gb@blockdiag(Wg)+bg)] @ W_lin + b_lin  (pipelined stages) ----
__global__ __launch_bounds__(256) void k_tail(const unsigned short* __restrict__ gb,
                                              const unsigned short* __restrict__ hb,
                                              const unsigned short* __restrict__ Wgt,
                                              const float* __restrict__ bg,
                                              const unsigned short* __restrict__ Wlt,  // [64][448]
                                              const float* __restrict__ bl,
                                              float* __restrict__ out) {
    __shared__ unsigned short As[64][72];   // A operand (hb, then gb head tiles)
    __shared__ unsigned short BsG[64][72];  // gat2 B (Wgt[hd])
    __shared__ unsigned short BsL[64][72];  // fin  B (Wlt block)
    __shared__ unsigned short Ct[64][72];   // gat2 output staging
    const int t  = threadIdx.x;
    const int n0 = blockIdx.x * 64;
    const int w = t >> 6, l = t & 63;
    const int fr = l & 15, fq = l >> 4;
    const int ar = t >> 2, ac = (t & 3) * 16;
    int arg = n0 + ar; if (arg >= NN) arg = NN - 1;

    f32x4 oacc[4];
    #pragma unroll
    for (int nb = 0; nb < 4; nb++) oacc[nb] = (f32x4){0.f, 0.f, 0.f, 0.f};

    // head-stage registers (double-buffer): gb tile, Wgt[hd], Wlt block
    uint4 gA, gB, G0, G1, M0, M1;
    {   // prologue: load head 0
        const uint4* gp = (const uint4*)(gb + (size_t)arg * FD + 0 * 64 + ac);
        gA = gp[0]; gB = gp[1];
        const uint4* wpg = (const uint4*)(Wgt + (size_t)0 * 4096 + ar * 64 + ac);
        G0 = wpg[0]; G1 = wpg[1];
        const uint4* wpl = (const uint4*)(Wlt + (size_t)ar * CATK + 64 + 0 * 64 + ac);
        M0 = wpl[0]; M1 = wpl[1];
    }
    {   // kt = 0: A = hb tile, B = Wlt[:, 0:64]
        const uint4* hp = (const uint4*)(hb + (size_t)arg * HIDD + ac);
        uint4 aA = hp[0], aB = hp[1];
        const uint4* wp = (const uint4*)(Wlt + (size_t)ar * CATK + 0 + ac);
        uint4 b0 = wp[0], b1 = wp[1];
        *(uint4*)&As[ar][ac]      = aA;
        *(uint4*)&As[ar][ac + 8]  = aB;
        *(uint4*)&BsL[ar][ac]     = b0;
        *(uint4*)&BsL[ar][ac + 8] = b1;
        __syncthreads();
        #pragma unroll
        for (int ks = 0; ks < 2; ks++) {
            short8 af = *(const short8*)&As[w * 16 + fr][ks * 32 + fq * 8];
            #pragma unroll
            for (int nb = 0; nb < 4; nb++) {
                short8 bf = *(const short8*)&BsL[nb * 16 + fr][ks * 32 + fq * 8];
                oacc[nb] = __builtin_amdgcn_mfma_f32_16x16x32_bf16(af, bf, oacc[nb], 0, 0, 0);
            }
        }
    }

    for (int hd = 0; hd < 6; hd++) {
        __syncthreads();   // previous iter's MFMA reads (As/BsG/BsL/Ct) complete
        {   // stage from registers
            *(uint4*)&As[ar][ac]      = gA;
            *(uint4*)&As[ar][ac + 8]  = gB;
            *(uint4*)&BsG[ar][ac]     = G0;
            *(uint4*)&BsG[ar][ac + 8] = G1;
            *(uint4*)&BsL[ar][ac]     = M0;
            *(uint4*)&BsL[ar][ac + 8] = M1;
        }
        __syncthreads();
        if (hd + 1 < 6) {   // issue NEXT head's loads; latency hides under both MFMA phases
            const uint4* gp = (const uint4*)(gb + (size_t)arg * FD + (hd + 1) * 64 + ac);
            gA = gp[0]; gB = gp[1];
            const uint4* wpg = (const uint4*)(Wgt + (size_t)(hd + 1) * 4096 + ar * 64 + ac);
            G0 = wpg[0]; G1 = wpg[1];
            const uint4* wpl = (const uint4*)(Wlt + (size_t)ar * CATK + 64 + (hd + 1) * 64 + ac);
            M0 = wpl[0]; M1 = wpl[1];
        }
        f32x4 acc2[4];
        #pragma unroll
        for (int nb = 0; nb < 4; nb++) acc2[nb] = (f32x4){0.f, 0.f, 0.f, 0.f};
        #pragma unroll
        for (int ks = 0; ks < 2; ks++) {
            short8 af = *(const short8*)&As[w * 16 + fr][ks * 32 + fq * 8];
            #pragma unroll
            for (int nb = 0; nb < 4; nb++) {
                short8 bf = *(const short8*)&BsG[nb * 16 + fr][ks * 32 + fq * 8];
                acc2[nb] = __builtin_amdgcn_mfma_f32_16x16x32_bf16(af, bf, acc2[nb], 0, 0, 0);
            }
        }
        #pragma unroll
        for (int nb = 0; nb < 4; nb++) {
            const int col = nb * 16 + fr;
            const float bias = bg[hd * 64 + col];
            #pragma unroll
            for (int r = 0; r < 4; r++)
                Ct[w * 16 + fq * 4 + r][col] = f2b(lrelu(acc2[nb][r] + bias, 0.01f));
        }
        __syncthreads();   // all Ct writes visible
        #pragma unroll
        for (int ks = 0; ks < 2; ks++) {
            short8 af = *(const short8*)&Ct[w * 16 + fr][ks * 32 + fq * 8];
            #pragma unroll
            for (int nb = 0; nb < 4; nb++) {
                short8 bf = *(const short8*)&BsL[nb * 16 + fr][ks * 32 + fq * 8];
                oacc[nb] = __builtin_amdgcn_mfma_f32_16x16x32_bf16(af, bf, oacc[nb], 0, 0, 0);
            }
        }
    }

    #pragma unroll
    for (int nb = 0; nb < 4; nb++) {
        const int col = nb * 16 + fr;
        const float bias = bl[col];
        #pragma unroll
        for (int r = 0; r < 4; r++) {
            const int row = n0 + w * 16 + fq * 4 + r;
            if (row < NN) out[(size_t)row * HIDD + col] = oacc[nb][r] + bias;
        }
    }
}

extern "C" void kernel_launch(void* const* d_in, const int* in_sizes, int n_in,
                              void* d_out, int out_size, void* d_ws, size_t ws_size,
                              hipStream_t stream) {
    const float* x   = (const float*)d_in[0];
    const int*   ei  = (const int*)d_in[1];
    // d_in[2] edge_weight: unused by the reference forward
    const float* Wp  = (const float*)d_in[3];
    const float* bp  = (const float*)d_in[4];
    const float* Wg  = (const float*)d_in[5];
    const float* ats = (const float*)d_in[6];
    const float* atd = (const float*)d_in[7];
    const float* bg  = (const float*)d_in[8];
    const float* Wl  = (const float*)d_in[9];
    const float* bl  = (const float*)d_in[10];
    float* out = (float*)d_out;

    char* ws_base = (char*)d_ws;
    size_t off = 0;
    auto alloc = [&](size_t bytes) -> char* {
        char* p = ws_base + off;
        off = (off + bytes + 255) & ~(size_t)255;
        return p;
    };
    unsigned short* hb      = (unsigned short*)alloc((size_t)NN * HIDD * 2);
    unsigned short* gb      = (unsigned short*)alloc((size_t)NN * FD * 2);
    float*          asrcP   = (float*)alloc((size_t)NN * 8 * 4);
    float*          adstP   = (float*)alloc((size_t)NN * 8 * 4);
    unsigned int*   counts  = (unsigned int*)alloc((size_t)NN * 4);
    unsigned int*   offsets = (unsigned int*)alloc((size_t)(NN + 1) * 4);
    unsigned int*   cursor  = (unsigned int*)alloc((size_t)NN * 4);
    unsigned int*   flag    = (unsigned int*)alloc(256);
    unsigned int*   bsum    = (unsigned int*)alloc((size_t)256 * 4);
    uint4*          edata   = (uint4*)alloc((size_t)EE * 16);
    unsigned short* Wt      = (unsigned short*)alloc((size_t)64 * CURD * 2);
    unsigned short* Wgt     = (unsigned short*)alloc((size_t)6 * 64 * 64 * 2);
    unsigned short* Wlt     = (unsigned short*)alloc((size_t)64 * CATK * 2);
    float*          wsv     = (float*)alloc((size_t)6 * 64 * 4);
    float*          wdv     = (float*)alloc((size_t)6 * 64 * 4);
    float*          bws     = (float*)alloc((size_t)8 * 4);
    float*          bwd     = (float*)alloc((size_t)8 * 4);
    if (off > ws_size) return;

    const int nb64 = (NN + 63) / 64;    // 782
    const int nbw  = (NN + 3) / 4;      // 12500
    const int nbs  = (NN + 255) / 256;  // 196

    hipLaunchKernelGGL(k_setup, dim3(B_TOT), dim3(256), 0, stream,
                       ei, Wp, bp, Wl, Wg, ats, atd, counts, cursor, flag,
                       Wt, Wlt, Wgt, wsv, wdv, bws, bwd);
    hipLaunchKernelGGL(k_pre,   dim3(nb64), dim3(256), 0, stream,
                       x, Wt, bp, wsv, wdv, bws, bwd, hb, asrcP, adstP);
    hipLaunchKernelGGL(k_hist,  dim3((EE + 255) / 256), dim3(256), 0, stream, ei, flag, counts);
    hipLaunchKernelGGL(k_bsum,  dim3(nbs), dim3(256), 0, stream, counts, bsum);
    hipLaunchKernelGGL(k_off,   dim3(nbs), dim3(256), 0, stream, counts, bsum, offsets);
    hipLaunchKernelGGL(k_fill,  dim3((EE + 255) / 256), dim3(256), 0, stream,
                       ei, flag, offsets, cursor, asrcP, adstP, edata);
    hipLaunchKernelGGL(k_agg,   dim3(nbw), dim3(256), 0, stream,
                       offsets, edata, asrcP, adstP, hb, gb);
    hipLaunchKernelGGL(k_tail,  dim3(nb64), dim3(256), 0, stream, gb, hb, Wgt, bg, Wlt, bl, out);
}

// Round 19
// 179.924 us; speedup vs baseline: 1.0440x; 1.0440x over previous
//
#include <hip/hip_runtime.h>
#include <hip/hip_bf16.h>

// GNN forward: pre-Linear -> GATConv(6 heads, self-loops, edge softmax) -> concat -> Linear
// FINAL (R19 = R15 config, best measured 180.3us):
// - Aggregation identity: sum_e coef_e*(h[s]@Wg) = (sum_e coef_e*h[s])@Wg -> gather 128B bf16 rows
// - a_src/a_dst computed as k_pre REGISTER EPILOGUE (f32 acc + shfl-reduce)
// - Self-loops handled inline in k_agg (edata/CSR hold only the EE real edges)
// - Per-edge softmax weights computed once in k_fill -> 16B f16 records {src, 6 x f16 w}
// - k_agg: readfirstlane scalar record loads, 8-edge unroll
// - k_tail: separate BsG/BsL LDS buffers -> 3 barriers/head
// Dead ends (measured): 80-col fused k_pre -> graph-replay divergence (R6/R7);
// launch-fusion bundles / single-block scan -> net negative (R12/R13); k_pre reg-pipeline,
// K-split TLP, barrier-free B-resident loops -> all null (R16-R18): k_pre's ~58us is a
// DRAM-stream latency floor for this access shape, not a scheduling artifact.
// N=50000, E=800000, CUR=512, HID=64, OUT=64, HEADS=6

#define NN    50000
#define EE    800000
#define CURD  512
#define HIDD  64
#define FD    384        // HEADS*OUT
#define CATK  448        // HID + FD

typedef __attribute__((ext_vector_type(8))) short short8;
typedef __attribute__((ext_vector_type(4))) float f32x4;

static __device__ __forceinline__ float b2f(unsigned short u) {
    union { unsigned int i; float f; } x; x.i = ((unsigned int)u) << 16; return x.f;
}
static __device__ __forceinline__ unsigned short f2b(float f) {
    unsigned int x = __float_as_uint(f);
    unsigned int r = (x + 0x7fffu + ((x >> 16) & 1u)) >> 16;
    return (unsigned short)r;
}
static __device__ __forceinline__ unsigned int packbf(float a, float b) {
    return (unsigned int)f2b(a) | ((unsigned int)f2b(b) << 16);
}
static __device__ __forceinline__ unsigned short f2h(float f) {
    _Float16 h = (_Float16)f; unsigned short u; __builtin_memcpy(&u, &h, 2); return u;
}
static __device__ __forceinline__ float h2f(unsigned short u) {
    _Float16 h; __builtin_memcpy(&h, &u, 2); return (float)h;
}
static __device__ __forceinline__ float lrelu(float v, float a) { return v > 0.f ? v : a * v; }

// ---------------- k_setup: init + detect + 3 weight transposes + watt(+bias proj) ----------
#define B_INIT 196
#define B_DET  196
#define B_TRWP 197            // 128 blocks: Wt[c][k]=Wp[k][c]
#define B_TRWL 325            // 112 blocks: Wlt[c][k]=Wl[k][c]
#define B_TRWG 437            // 96 blocks:  Wgt[h][c][k]=Wg[k][h*64+c]
#define B_WATT 533            // 2 blocks:   wsv/wdv[h][k] + bws/bwd[h]
#define B_TOT  535

__global__ void k_setup(const int* __restrict__ ei,
                        const float* __restrict__ Wp, const float* __restrict__ bp,
                        const float* __restrict__ Wl, const float* __restrict__ Wg,
                        const float* __restrict__ atts, const float* __restrict__ attd,
                        unsigned int* __restrict__ counts, unsigned int* __restrict__ cursor,
                        unsigned int* __restrict__ flag,
                        unsigned short* __restrict__ Wt, unsigned short* __restrict__ Wlt,
                        unsigned short* __restrict__ Wgt,
                        float* __restrict__ wsv, float* __restrict__ wdv,
                        float* __restrict__ bws, float* __restrict__ bwd) {
    __shared__ unsigned int anyv;
    const int b = blockIdx.x, t = threadIdx.x;
    if (b < B_INIT) {
        int i = b * 256 + t;
        if (i < NN) { counts[i] = 0u; cursor[i] = 0u; }
    } else if (b == B_DET) {
        if (t == 0) anyv = 0u;
        __syncthreads();
        unsigned int v = 0;
        for (int i = t; i < 2048; i += 256) v |= (unsigned int)ei[2 * i + 1];
        atomicOr(&anyv, v);
        __syncthreads();
        if (t == 0) *flag = (anyv == 0u) ? 1u : 0u;   // 1 => int64 layout
    } else if (b < B_TRWL) {
        int i = (b - B_TRWP) * 256 + t;               // Wt[c][k]=Wp[k][c], K=512
        int c = i >> 9, k = i & 511;
        Wt[i] = f2b(Wp[k * 64 + c]);
    } else if (b < B_TRWG) {
        int i = (b - B_TRWL) * 256 + t;
        if (i < 64 * CATK) {
            int c = i / CATK, k = i - c * CATK;
            Wlt[i] = f2b(Wl[k * 64 + c]);
        }
    } else if (b < B_WATT) {
        int i = (b - B_TRWG) * 256 + t;
        int hd = i >> 12, rem = i & 4095, c = rem >> 6, k = rem & 63;
        Wgt[i] = f2b(Wg[k * FD + hd * 64 + c]);
    } else {
        int j = (b - B_WATT) * 256 + t;               // 384 total; whole waves valid/invalid
        if (j < 384) {
            int hd = j >> 6, k = j & 63;
            float s = 0.f, d = 0.f;
            for (int c = 0; c < 64; c++) {
                float w = Wg[k * FD + hd * 64 + c];
                s = fmaf(w, atts[hd * 64 + c], s);
                d = fmaf(w, attd[hd * 64 + c], d);
            }
            wsv[j] = s; wdv[j] = d;
            float pbs = bp[k] * s, pbd = bp[k] * d;
            #pragma unroll
            for (int o = 32; o > 0; o >>= 1) {
                pbs += __shfl_xor(pbs, o, 64);
                pbd += __shfl_xor(pbd, o, 64);
            }
            if ((t & 63) == 0) { bws[hd] = pbs; bwd[hd] = pbd; }
        }
    }
}

// ---- K1: hb = bf16(x @ W_pre + b_pre); epilogue computes asrcP/adstP from f32 acc ----
__global__ __launch_bounds__(256) void k_pre(const float* __restrict__ x,
                                             const unsigned short* __restrict__ Wt,
                                             const float* __restrict__ bp,
                                             const float* __restrict__ wsv,
                                             const float* __restrict__ wdv,
                                             const float* __restrict__ bws,
                                             const float* __restrict__ bwd,
                                             unsigned short* __restrict__ hb,
                                             float* __restrict__ asrcP, float* __restrict__ adstP) {
    __shared__ unsigned short As[64][72];
    __shared__ unsigned short Bs[64][72];
    const int t  = threadIdx.x;
    const int n0 = blockIdx.x * 64;
    const int w = t >> 6, l = t & 63;
    const int fr = l & 15, fq = l >> 4;
    const int ar = t >> 2, ac = (t & 3) * 16;
    int arg = n0 + ar; if (arg >= NN) arg = NN - 1;
    f32x4 acc[4];
    #pragma unroll
    for (int nb = 0; nb < 4; nb++) acc[nb] = (f32x4){0.f, 0.f, 0.f, 0.f};

    for (int kt = 0; kt < CURD; kt += 64) {
        const float4* xp = (const float4*)(x + (size_t)arg * CURD + kt + ac);
        float4 a0 = xp[0], a1 = xp[1], a2 = xp[2], a3 = xp[3];
        const uint4* wp = (const uint4*)(Wt + (size_t)ar * CURD + kt + ac);
        uint4 b0 = wp[0], b1 = wp[1];
        __syncthreads();
        *(uint4*)&As[ar][ac]     = make_uint4(packbf(a0.x,a0.y), packbf(a0.z,a0.w),
                                              packbf(a1.x,a1.y), packbf(a1.z,a1.w));
        *(uint4*)&As[ar][ac + 8] = make_uint4(packbf(a2.x,a2.y), packbf(a2.z,a2.w),
                                              packbf(a3.x,a3.y), packbf(a3.z,a3.w));
        *(uint4*)&Bs[ar][ac]     = b0;
        *(uint4*)&Bs[ar][ac + 8] = b1;
        __syncthreads();
        #pragma unroll
        for (int ks = 0; ks < 2; ks++) {
            short8 af = *(const short8*)&As[w * 16 + fr][ks * 32 + fq * 8];
            #pragma unroll
            for (int nb = 0; nb < 4; nb++) {
                short8 bf = *(const short8*)&Bs[nb * 16 + fr][ks * 32 + fq * 8];
                acc[nb] = __builtin_amdgcn_mfma_f32_16x16x32_bf16(af, bf, acc[nb], 0, 0, 0);
            }
        }
    }
    #pragma unroll
    for (int nb = 0; nb < 4; nb++) {
        const int col = nb * 16 + fr;
        const float bias = bp[col];
        #pragma unroll
        for (int r = 0; r < 4; r++) {
            const int row = n0 + w * 16 + fq * 4 + r;
            if (row < NN) hb[(size_t)row * HIDD + col] = f2b(acc[nb][r] + bias);
        }
    }
    // attention-logit epilogue: asrc[row][hd] = sum_col acc[row][col]*wsv[hd][col] + bws[hd]
    for (int hd = 0; hd < 6; hd++) {
        float wsl[4], wdl[4];
        #pragma unroll
        for (int nb = 0; nb < 4; nb++) {
            wsl[nb] = wsv[hd * 64 + nb * 16 + fr];
            wdl[nb] = wdv[hd * 64 + nb * 16 + fr];
        }
        float ps[4], pd[4];
        #pragma unroll
        for (int r = 0; r < 4; r++) {
            ps[r] = acc[0][r] * wsl[0];
            pd[r] = acc[0][r] * wdl[0];
            #pragma unroll
            for (int nb = 1; nb < 4; nb++) {
                ps[r] = fmaf(acc[nb][r], wsl[nb], ps[r]);
                pd[r] = fmaf(acc[nb][r], wdl[nb], pd[r]);
            }
        }
        #pragma unroll
        for (int o = 1; o < 16; o <<= 1) {
            #pragma unroll
            for (int r = 0; r < 4; r++) {
                ps[r] += __shfl_xor(ps[r], o, 64);
                pd[r] += __shfl_xor(pd[r], o, 64);
            }
        }
        if (fr == 0) {
            const float bs = bws[hd], bd = bwd[hd];
            #pragma unroll
            for (int r = 0; r < 4; r++) {
                const int row = n0 + w * 16 + fq * 4 + r;
                if (row < NN) {
                    asrcP[(size_t)row * 8 + hd] = ps[r] + bs;
                    adstP[(size_t)row * 8 + hd] = pd[r] + bd;
                }
            }
        }
    }
}

// ---------------- in-degree histogram (real edges only) ----------------
__global__ void k_hist(const int* __restrict__ ei, const unsigned int* __restrict__ flag,
                       unsigned int* __restrict__ counts) {
    int e = blockIdx.x * 256 + threadIdx.x;
    if (e >= EE) return;
    const bool wide = (*flag != 0u);
    int d = wide ? ei[2 * (EE + e)] : ei[EE + e];
    atomicAdd(&counts[d], 1u);
}

// ---------------- scan phase 1: per-block sums ----------------
__global__ __launch_bounds__(256) void k_bsum(const unsigned int* __restrict__ counts,
                                              unsigned int* __restrict__ bsum) {
    __shared__ unsigned int wt[4];
    const int t = threadIdx.x, w = t >> 6, l = t & 63;
    int i = blockIdx.x * 256 + t;
    unsigned int v = (i < NN) ? counts[i] : 0u;
    #pragma unroll
    for (int o = 32; o > 0; o >>= 1) v += __shfl_xor(v, o, 64);
    if (l == 0) wt[w] = v;
    __syncthreads();
    if (t == 0) bsum[blockIdx.x] = wt[0] + wt[1] + wt[2] + wt[3];
}

// ---------------- scan phase 2: offsets (inline redundant scan of 196 block sums) ----------------
__global__ __launch_bounds__(256) void k_off(const unsigned int* __restrict__ counts,
                                             const unsigned int* __restrict__ bsum,
                                             unsigned int* __restrict__ offsets) {
    __shared__ unsigned int sc[256];
    __shared__ unsigned int wt[4];
    const int t = threadIdx.x, w = t >> 6, l = t & 63;
    const int nb = (NN + 255) / 256;   // 196
    unsigned int bv = (t < nb) ? bsum[t] : 0u;
    sc[t] = bv;
    __syncthreads();
    for (int o = 1; o < 256; o <<= 1) {
        unsigned int xv = (t >= o) ? sc[t - o] : 0u;
        __syncthreads();
        sc[t] += xv;
        __syncthreads();
    }
    const unsigned int bpre = sc[blockIdx.x] -
        ((blockIdx.x < nb) ? bsum[blockIdx.x] : 0u);   // exclusive prefix for this block

    int i = blockIdx.x * 256 + t;
    unsigned int v = (i < NN) ? counts[i] : 0u;
    unsigned int incl = v;
    #pragma unroll
    for (int o = 1; o < 64; o <<= 1) {
        unsigned int xv = __shfl_up(incl, o, 64);
        if (l >= o) incl += xv;
    }
    if (l == 63) wt[w] = incl;
    __syncthreads();
    unsigned int woff = 0;
    #pragma unroll
    for (int ww = 0; ww < 4; ww++) woff += (ww < w) ? wt[ww] : 0u;
    const unsigned int base = bpre + woff;
    if (i < NN) offsets[i] = base + incl - v;
    if (i == NN - 1) offsets[NN] = base + incl;
}

// ---------------- CSR fill + per-edge weights: edata[pos] = {src, 6 x f16 w} (16B) ----------------
__global__ void k_fill(const int* __restrict__ ei, const unsigned int* __restrict__ flag,
                       const unsigned int* __restrict__ offsets, unsigned int* __restrict__ cursor,
                       const float* __restrict__ asrcP, const float* __restrict__ adstP,
                       uint4* __restrict__ edata) {
    int e = blockIdx.x * 256 + threadIdx.x;
    if (e >= EE) return;
    const bool wide = (*flag != 0u);
    const int s = wide ? ei[2 * e] : ei[e];
    const int d = wide ? ei[2 * (EE + e)] : ei[EE + e];
    unsigned int pos = offsets[d] + atomicAdd(&cursor[d], 1u);
    const float4 s0 = *(const float4*)(asrcP + (size_t)s * 8);
    const float2 s1 = *(const float2*)(asrcP + (size_t)s * 8 + 4);
    const float4 d0 = *(const float4*)(adstP + (size_t)d * 8);
    const float2 d1 = *(const float2*)(adstP + (size_t)d * 8 + 4);
    const float as[6] = {s0.x, s0.y, s0.z, s0.w, s1.x, s1.y};
    const float ad[6] = {d0.x, d0.y, d0.z, d0.w, d1.x, d1.y};
    unsigned short wh[6];
    #pragma unroll
    for (int hd = 0; hd < 6; hd++) {
        float a = as[hd] + ad[hd];
        a = fmaxf(a, 0.2f * a);                 // leaky_relu 0.2
        wh[hd] = f2h(__expf(a));                // shift skipped: alpha O(1), softmax shift-invariant
    }
    uint4 u;
    u.x = (unsigned int)s;
    u.y = (unsigned int)wh[0] | ((unsigned int)wh[1] << 16);
    u.z = (unsigned int)wh[2] | ((unsigned int)wh[3] << 16);
    u.w = (unsigned int)wh[4] | ((unsigned int)wh[5] << 16);
    edata[pos] = u;
}

// ---- k_agg: self-loop inline + scalar f16-record loads (8-edge unroll) + row gather ----
#define W6H(u, nm) \
    const float nm[6] = {h2f(u.y & 0xffff), h2f(u.y >> 16), h2f(u.z & 0xffff), \
                         h2f(u.z >> 16),    h2f(u.w & 0xffff), h2f(u.w >> 16)};

__global__ __launch_bounds__(256) void k_agg(const unsigned int* __restrict__ offsets,
                                             const uint4* __restrict__ edata,
                                             const float* __restrict__ asrcP,
                                             const float* __restrict__ adstP,
                                             const unsigned short* __restrict__ hb,
                                             unsigned short* __restrict__ gb) {
    const int n = blockIdx.x * 4 + (threadIdx.x >> 6);  // one wave per node
    if (n >= NN) return;
    const int l = threadIdx.x & 63;
    const unsigned int e0 = __builtin_amdgcn_readfirstlane(offsets[n]);
    const unsigned int e1 = __builtin_amdgcn_readfirstlane(offsets[n + 1]);
    float acc[6], den[6];
    {   // self loop: w = exp(lrelu(asrc[n]+adst[n])), contribution w*hb[n]
        const float4 a0 = *(const float4*)(asrcP + (size_t)n * 8);
        const float2 a1 = *(const float2*)(asrcP + (size_t)n * 8 + 4);
        const float4 d0 = *(const float4*)(adstP + (size_t)n * 8);
        const float2 d1 = *(const float2*)(adstP + (size_t)n * 8 + 4);
        const float as[6] = {a0.x, a0.y, a0.z, a0.w, a1.x, a1.y};
        const float ad[6] = {d0.x, d0.y, d0.z, d0.w, d1.x, d1.y};
        const float hvn = b2f(hb[(size_t)n * HIDD + l]);
        #pragma unroll
        for (int hd = 0; hd < 6; hd++) {
            float a = as[hd] + ad[hd];
            a = fmaxf(a, 0.2f * a);
            const float wv = __expf(a);
            acc[hd] = wv * hvn;
            den[hd] = wv;
        }
    }

    unsigned int e = e0;
    for (; e + 8 <= e1; e += 8) {
        const unsigned int eu = __builtin_amdgcn_readfirstlane(e);  // uniform -> s_load records
        uint4 r[8];
        #pragma unroll
        for (int j = 0; j < 8; j++) r[j] = edata[(size_t)eu + j];
        float hv[8];
        #pragma unroll
        for (int j = 0; j < 8; j++) hv[j] = b2f(hb[(size_t)r[j].x * HIDD + l]);
        #pragma unroll
        for (int j = 0; j < 8; j++) {
            W6H(r[j], wj)
            #pragma unroll
            for (int hd = 0; hd < 6; hd++) {
                acc[hd] = fmaf(wj[hd], hv[j], acc[hd]);
                den[hd] += wj[hd];
            }
        }
    }
    for (; e + 4 <= e1; e += 4) {
        const unsigned int eu = __builtin_amdgcn_readfirstlane(e);
        uint4 r[4];
        #pragma unroll
        for (int j = 0; j < 4; j++) r[j] = edata[(size_t)eu + j];
        float hv[4];
        #pragma unroll
        for (int j = 0; j < 4; j++) hv[j] = b2f(hb[(size_t)r[j].x * HIDD + l]);
        #pragma unroll
        for (int j = 0; j < 4; j++) {
            W6H(r[j], wj)
            #pragma unroll
            for (int hd = 0; hd < 6; hd++) {
                acc[hd] = fmaf(wj[hd], hv[j], acc[hd]);
                den[hd] += wj[hd];
            }
        }
    }
    for (; e < e1; e++) {
        const unsigned int eu = __builtin_amdgcn_readfirstlane(e);
        const uint4 u = edata[(size_t)eu];
        const float hv = b2f(hb[(size_t)u.x * HIDD + l]);
        W6H(u, wv)
        #pragma unroll
        for (int hd = 0; hd < 6; hd++) {
            acc[hd] = fmaf(wv[hd], hv, acc[hd]);
            den[hd] += wv[hd];
        }
    }
    #pragma unroll
    for (int hd = 0; hd < 6; hd++)
        gb[(size_t)n * FD + hd * 64 + l] = f2b(acc[hd] / den[hd]);
}

// ---- k_tail: out = [hb | lrelu(gb@blockdiag(Wg)+bg)] @ W_lin + b_lin  (3 barriers/head) ----
__global__ __launch_bounds__(256) void k_tail(const unsigned short* __restrict__ gb,
                                              const unsigned short* __restrict__ hb,
                                              const unsigned short* __restrict__ Wgt,
                                              const float* __restrict__ bg,
                                              const unsigned short* __restrict__ Wlt,  // [64][448]
                                              const float* __restrict__ bl,
                                              float* __restrict__ out) {
    __shared__ unsigned short As[64][72];   // A operand (hb, then gb head tiles)
    __shared__ unsigned short BsG[64][72];  // gat2 B (Wgt[hd])
    __shared__ unsigned short BsL[64][72];  // fin  B (Wlt block)
    __shared__ unsigned short Ct[64][72];   // gat2 output staging
    const int t  = threadIdx.x;
    const int n0 = blockIdx.x * 64;
    const int w = t >> 6, l = t & 63;
    const int fr = l & 15, fq = l >> 4;
    const int ar = t >> 2, ac = (t & 3) * 16;
    int arg = n0 + ar; if (arg >= NN) arg = NN - 1;

    f32x4 oacc[4];
    #pragma unroll
    for (int nb = 0; nb < 4; nb++) oacc[nb] = (f32x4){0.f, 0.f, 0.f, 0.f};

    {   // kt = 0: A = hb tile, B = Wlt[:, 0:64]
        const uint4* hp = (const uint4*)(hb + (size_t)arg * HIDD + ac);
        uint4 aA = hp[0], aB = hp[1];
        const uint4* wp = (const uint4*)(Wlt + (size_t)ar * CATK + 0 + ac);
        uint4 b0 = wp[0], b1 = wp[1];
        *(uint4*)&As[ar][ac]      = aA;
        *(uint4*)&As[ar][ac + 8]  = aB;
        *(uint4*)&BsL[ar][ac]     = b0;
        *(uint4*)&BsL[ar][ac + 8] = b1;
        __syncthreads();
        #pragma unroll
        for (int ks = 0; ks < 2; ks++) {
            short8 af = *(const short8*)&As[w * 16 + fr][ks * 32 + fq * 8];
            #pragma unroll
            for (int nb = 0; nb < 4; nb++) {
                short8 bf = *(const short8*)&BsL[nb * 16 + fr][ks * 32 + fq * 8];
                oacc[nb] = __builtin_amdgcn_mfma_f32_16x16x32_bf16(af, bf, oacc[nb], 0, 0, 0);
            }
        }
    }

    for (int hd = 0; hd < 6; hd++) {
        __syncthreads();   // previous iter's MFMA reads (As/BsG/BsL/Ct) complete
        {   // stage A = gb tile (head hd), BsG = Wgt[hd], BsL = Wlt[:, 64+hd*64 ..]
            const uint4* gp = (const uint4*)(gb + (size_t)arg * FD + hd * 64 + ac);
            uint4 aA = gp[0], aB = gp[1];
            const uint4* wpg = (const uint4*)(Wgt + (size_t)hd * 4096 + ar * 64 + ac);
            uint4 g0 = wpg[0], g1 = wpg[1];
            const uint4* wpl = (const uint4*)(Wlt + (size_t)ar * CATK + 64 + hd * 64 + ac);
            uint4 l0 = wpl[0], l1 = wpl[1];
            *(uint4*)&As[ar][ac]      = aA;
            *(uint4*)&As[ar][ac + 8]  = aB;
            *(uint4*)&BsG[ar][ac]     = g0;
            *(uint4*)&BsG[ar][ac + 8] = g1;
            *(uint4*)&BsL[ar][ac]     = l0;
            *(uint4*)&BsL[ar][ac + 8] = l1;
        }
        __syncthreads();
        f32x4 acc2[4];
        #pragma unroll
        for (int nb = 0; nb < 4; nb++) acc2[nb] = (f32x4){0.f, 0.f, 0.f, 0.f};
        #pragma unroll
        for (int ks = 0; ks < 2; ks++) {
            short8 af = *(const short8*)&As[w * 16 + fr][ks * 32 + fq * 8];
            #pragma unroll
            for (int nb = 0; nb < 4; nb++) {
                short8 bf = *(const short8*)&BsG[nb * 16 + fr][ks * 32 + fq * 8];
                acc2[nb] = __builtin_amdgcn_mfma_f32_16x16x32_bf16(af, bf, acc2[nb], 0, 0, 0);
            }
        }
        #pragma unroll
        for (int nb = 0; nb < 4; nb++) {
            const int col = nb * 16 + fr;
            const float bias = bg[hd * 64 + col];
            #pragma unroll
            for (int r = 0; r < 4; r++)
                Ct[w * 16 + fq * 4 + r][col] = f2b(lrelu(acc2[nb][r] + bias, 0.01f));
        }
        __syncthreads();   // all Ct writes visible
        #pragma unroll
        for (int ks = 0; ks < 2; ks++) {
            short8 af = *(const short8*)&Ct[w * 16 + fr][ks * 32 + fq * 8];
            #pragma unroll
            for (int nb = 0; nb < 4; nb++) {
                short8 bf = *(const short8*)&BsL[nb * 16 + fr][ks * 32 + fq * 8];
                oacc[nb] = __builtin_amdgcn_mfma_f32_16x16x32_bf16(af, bf, oacc[nb], 0, 0, 0);
            }
        }
    }

    #pragma unroll
    for (int nb = 0; nb < 4; nb++) {
        const int col = nb * 16 + fr;
        const float bias = bl[col];
        #pragma unroll
        for (int r = 0; r < 4; r++) {
            const int row = n0 + w * 16 + fq * 4 + r;
            if (row < NN) out[(size_t)row * HIDD + col] = oacc[nb][r] + bias;
        }
    }
}

extern "C" void kernel_launch(void* const* d_in, const int* in_sizes, int n_in,
                              void* d_out, int out_size, void* d_ws, size_t ws_size,
                              hipStream_t stream) {
    const float* x   = (const float*)d_in[0];
    const int*   ei  = (const int*)d_in[1];
    // d_in[2] edge_weight: unused by the reference forward
    const float* Wp  = (const float*)d_in[3];
    const float* bp  = (const float*)d_in[4];
    const float* Wg  = (const float*)d_in[5];
    const float* ats = (const float*)d_in[6];
    const float* atd = (const float*)d_in[7];
    const float* bg  = (const float*)d_in[8];
    const float* Wl  = (const float*)d_in[9];
    const float* bl  = (const float*)d_in[10];
    float* out = (float*)d_out;

    char* ws_base = (char*)d_ws;
    size_t off = 0;
    auto alloc = [&](size_t bytes) -> char* {
        char* p = ws_base + off;
        off = (off + bytes + 255) & ~(size_t)255;
        return p;
    };
    unsigned short* hb      = (unsigned short*)alloc((size_t)NN * HIDD * 2);
    unsigned short* gb      = (unsigned short*)alloc((size_t)NN * FD * 2);
    float*          asrcP   = (float*)alloc((size_t)NN * 8 * 4);
    float*          adstP   = (float*)alloc((size_t)NN * 8 * 4);
    unsigned int*   counts  = (unsigned int*)alloc((size_t)NN * 4);
    unsigned int*   offsets = (unsigned int*)alloc((size_t)(NN + 1) * 4);
    unsigned int*   cursor  = (unsigned int*)alloc((size_t)NN * 4);
    unsigned int*   flag    = (unsigned int*)alloc(256);
    unsigned int*   bsum    = (unsigned int*)alloc((size_t)256 * 4);
    uint4*          edata   = (uint4*)alloc((size_t)EE * 16);
    unsigned short* Wt      = (unsigned short*)alloc((size_t)64 * CURD * 2);
    unsigned short* Wgt     = (unsigned short*)alloc((size_t)6 * 64 * 64 * 2);
    unsigned short* Wlt     = (unsigned short*)alloc((size_t)64 * CATK * 2);
    float*          wsv     = (float*)alloc((size_t)6 * 64 * 4);
    float*          wdv     = (float*)alloc((size_t)6 * 64 * 4);
    float*          bws     = (float*)alloc((size_t)8 * 4);
    float*          bwd     = (float*)alloc((size_t)8 * 4);
    if (off > ws_size) return;

    const int nb64 = (NN + 63) / 64;    // 782
    const int nbw  = (NN + 3) / 4;      // 12500
    const int nbs  = (NN + 255) / 256;  // 196

    hipLaunchKernelGGL(k_setup, dim3(B_TOT), dim3(256), 0, stream,
                       ei, Wp, bp, Wl, Wg, ats, atd, counts, cursor, flag,
                       Wt, Wlt, Wgt, wsv, wdv, bws, bwd);
    hipLaunchKernelGGL(k_pre,   dim3(nb64), dim3(256), 0, stream,
                       x, Wt, bp, wsv, wdv, bws, bwd, hb, asrcP, adstP);
    hipLaunchKernelGGL(k_hist,  dim3((EE + 255) / 256), dim3(256), 0, stream, ei, flag, counts);
    hipLaunchKernelGGL(k_bsum,  dim3(nbs), dim3(256), 0, stream, counts, bsum);
    hipLaunchKernelGGL(k_off,   dim3(nbs), dim3(256), 0, stream, counts, bsum, offsets);
    hipLaunchKernelGGL(k_fill,  dim3((EE + 255) / 256), dim3(256), 0, stream,
                       ei, flag, offsets, cursor, asrcP, adstP, edata);
    hipLaunchKernelGGL(k_agg,   dim3(nbw), dim3(256), 0, stream,
                       offsets, edata, asrcP, adstP, hb, gb);
    hipLaunchKernelGGL(k_tail,  dim3(nb64), dim3(256), 0, stream, gb, hb, Wgt, bg, Wlt, bl, out);
}